// Round 1
// baseline (866.421 us; speedup 1.0000x reference)
//
#include <hip/hip_runtime.h>
#include <hip/hip_bf16.h>
#include <cstdint>
#include <cstddef>

// ---------------------------------------------------------------------------
// NostARHeadAttention: LN -> {Q(last), K, V} proj -> RoPE(K) -> 1-query attn
// -> out proj.  B=8, S=2048, E=2048, H=16, D=128, ROT=64, PAD=50257.
// Heavy op: KV projection (16384x2048)@(2048x4096) -> bf16 MFMA GEMM (m97
// structure: 128x128 tile, BK=32, global_load_lds width=16).
// ---------------------------------------------------------------------------

using bf16x8 = __attribute__((ext_vector_type(8))) __bf16;
using f32x4  = __attribute__((ext_vector_type(4))) float;
using us8    = __attribute__((ext_vector_type(8))) unsigned short;

__device__ __forceinline__ float bf2f(unsigned short u) {
  return __uint_as_float(((unsigned)u) << 16);
}
__device__ __forceinline__ unsigned short f2bf(float f) {
  unsigned u = __float_as_uint(f);
  u += 0x7fffu + ((u >> 16) & 1u);   // RNE
  return (unsigned short)(u >> 16);
}

__device__ __forceinline__ void gld16(const void* g, void* l) {
  // global -> LDS async, 16B per lane; LDS dest = wave-uniform base + lane*16
  __builtin_amdgcn_global_load_lds((__attribute__((address_space(1))) void*)g,
                                   (__attribute__((address_space(3))) void*)l,
                                   16, 0, 0);
}

// ---------------------------------------------------------------------------
// 1. last non-pad index per batch (argmax of cumsum of mask == last non-pad)
// ---------------------------------------------------------------------------
__global__ __launch_bounds__(256) void ix_kernel(const int* __restrict__ ids,
                                                 int* __restrict__ ixp) {
  const int b = blockIdx.x, tid = threadIdx.x;
  int best = -1;
  for (int t = tid; t < 2048; t += 256)
    if (ids[b * 2048 + t] != 50257) best = (t > best) ? t : best;
  for (int m = 1; m < 64; m <<= 1) {
    int o = __shfl_xor(best, m);
    best = (o > best) ? o : best;
  }
  __shared__ int rb[4];
  if ((tid & 63) == 0) rb[tid >> 6] = best;
  __syncthreads();
  if (tid == 0) {
    int r = rb[0];
    for (int w = 1; w < 4; ++w) r = (rb[w] > r) ? rb[w] : r;
    ixp[b] = (r < 0) ? 0 : r;
  }
}

// ---------------------------------------------------------------------------
// 2. LayerNorm all rows -> bf16
// ---------------------------------------------------------------------------
__global__ __launch_bounds__(256) void ln_kernel(const float* __restrict__ x,
                                                 const float* __restrict__ gw,
                                                 const float* __restrict__ gb,
                                                 unsigned short* __restrict__ y) {
  const size_t row = blockIdx.x;
  const float* xr = x + row * 2048;
  const int tid = threadIdx.x;
  float4 a = ((const float4*)xr)[tid];
  float4 b = ((const float4*)xr)[tid + 256];
  float s  = a.x + a.y + a.z + a.w + b.x + b.y + b.z + b.w;
  float ss = a.x*a.x + a.y*a.y + a.z*a.z + a.w*a.w +
             b.x*b.x + b.y*b.y + b.z*b.z + b.w*b.w;
  for (int m = 1; m < 64; m <<= 1) { s += __shfl_xor(s, m); ss += __shfl_xor(ss, m); }
  __shared__ float rs[4], rss[4];
  const int wave = tid >> 6, lane = tid & 63;
  if (lane == 0) { rs[wave] = s; rss[wave] = ss; }
  __syncthreads();
  s  = rs[0] + rs[1] + rs[2] + rs[3];
  ss = rss[0] + rss[1] + rss[2] + rss[3];
  const float mu = s * (1.f / 2048.f);
  const float var = ss * (1.f / 2048.f) - mu * mu;
  const float r = rsqrtf(var + 1e-5f);
  unsigned short o[8];
  const int i0 = tid * 4, i1 = 1024 + tid * 4;
  o[0] = f2bf((a.x - mu) * r * gw[i0 + 0] + gb[i0 + 0]);
  o[1] = f2bf((a.y - mu) * r * gw[i0 + 1] + gb[i0 + 1]);
  o[2] = f2bf((a.z - mu) * r * gw[i0 + 2] + gb[i0 + 2]);
  o[3] = f2bf((a.w - mu) * r * gw[i0 + 3] + gb[i0 + 3]);
  o[4] = f2bf((b.x - mu) * r * gw[i1 + 0] + gb[i1 + 0]);
  o[5] = f2bf((b.y - mu) * r * gw[i1 + 1] + gb[i1 + 1]);
  o[6] = f2bf((b.z - mu) * r * gw[i1 + 2] + gb[i1 + 2]);
  o[7] = f2bf((b.w - mu) * r * gw[i1 + 3] + gb[i1 + 3]);
  ushort4 p0 = {o[0], o[1], o[2], o[3]};
  ushort4 p1 = {o[4], o[5], o[6], o[7]};
  *(ushort4*)(y + row * 2048 + i0) = p0;
  *(ushort4*)(y + row * 2048 + i1) = p1;
}

// ---------------------------------------------------------------------------
// 3. fp32 -> bf16 weight convert (k_w / v_w), 4 elems per thread
// ---------------------------------------------------------------------------
__global__ __launch_bounds__(256) void f2bf_kernel(const float* __restrict__ src,
                                                   unsigned short* __restrict__ dst) {
  const size_t i = (size_t)blockIdx.x * 256 + threadIdx.x;   // float4 index
  float4 v = ((const float4*)src)[i];
  ushort4 o = {f2bf(v.x), f2bf(v.y), f2bf(v.z), f2bf(v.w)};
  ((ushort4*)dst)[i] = o;
}

// ---------------------------------------------------------------------------
// 4. sin/cos table: tab[t*64 + i] = sin(t * 10000^(-i/32)), +32 -> cos
// ---------------------------------------------------------------------------
__global__ void sctab_kernel(float* __restrict__ tab) {
  const int t = blockIdx.x, tid = threadIdx.x;   // 64 threads
  const int i = tid & 31;
  const float inv = powf(10000.f, -(float)i / 32.f);
  const float ang = (float)t * inv;
  tab[t * 64 + tid] = (tid < 32) ? sinf(ang) : cosf(ang);
}

// ---------------------------------------------------------------------------
// 5. LN of the last-token row per batch -> fp32 (for exact Q path)
// ---------------------------------------------------------------------------
__global__ __launch_bounds__(256) void hlast_kernel(const float* __restrict__ x,
                                                    const float* __restrict__ gw,
                                                    const float* __restrict__ gb,
                                                    const int* __restrict__ ixp,
                                                    float* __restrict__ hl) {
  const int b = blockIdx.x;
  const size_t row = (size_t)b * 2048 + ixp[b];
  const float* xr = x + row * 2048;
  const int tid = threadIdx.x;
  float4 a = ((const float4*)xr)[tid];
  float4 c = ((const float4*)xr)[tid + 256];
  float s  = a.x + a.y + a.z + a.w + c.x + c.y + c.z + c.w;
  float ss = a.x*a.x + a.y*a.y + a.z*a.z + a.w*a.w +
             c.x*c.x + c.y*c.y + c.z*c.z + c.w*c.w;
  for (int m = 1; m < 64; m <<= 1) { s += __shfl_xor(s, m); ss += __shfl_xor(ss, m); }
  __shared__ float rs[4], rss[4];
  const int wave = tid >> 6, lane = tid & 63;
  if (lane == 0) { rs[wave] = s; rss[wave] = ss; }
  __syncthreads();
  s  = rs[0] + rs[1] + rs[2] + rs[3];
  ss = rss[0] + rss[1] + rss[2] + rss[3];
  const float mu = s * (1.f / 2048.f);
  const float var = ss * (1.f / 2048.f) - mu * mu;
  const float r = rsqrtf(var + 1e-5f);
  const int i0 = tid * 4, i1 = 1024 + tid * 4;
  float* yo = hl + (size_t)b * 2048;
  yo[i0 + 0] = (a.x - mu) * r * gw[i0 + 0] + gb[i0 + 0];
  yo[i0 + 1] = (a.y - mu) * r * gw[i0 + 1] + gb[i0 + 1];
  yo[i0 + 2] = (a.z - mu) * r * gw[i0 + 2] + gb[i0 + 2];
  yo[i0 + 3] = (a.w - mu) * r * gw[i0 + 3] + gb[i0 + 3];
  yo[i1 + 0] = (c.x - mu) * r * gw[i1 + 0] + gb[i1 + 0];
  yo[i1 + 1] = (c.y - mu) * r * gw[i1 + 1] + gb[i1 + 1];
  yo[i1 + 2] = (c.z - mu) * r * gw[i1 + 2] + gb[i1 + 2];
  yo[i1 + 3] = (c.w - mu) * r * gw[i1 + 3] + gb[i1 + 3];
}

// ---------------------------------------------------------------------------
// 6. GEMV: Y[8][2048] = X[8][2048] @ W^T + bias   (fp32; used for Q and OUT)
//    32 blocks x 64 outputs; wave handles 16 outputs, lanes split K.
// ---------------------------------------------------------------------------
__global__ __launch_bounds__(256) void gemv8_kernel(const float* __restrict__ X,
                                                    const float* __restrict__ W,
                                                    const float* __restrict__ bias,
                                                    float* __restrict__ Y) {
  __shared__ float Xs[8 * 2048];   // 64 KiB
  const int tid = threadIdx.x;
  for (int i = tid; i < 4096; i += 256) ((float4*)Xs)[i] = ((const float4*)X)[i];
  __syncthreads();
  const int wave = tid >> 6, lane = tid & 63;
  const int e0 = blockIdx.x * 64 + wave * 16;
  for (int s = 0; s < 16; ++s) {
    const int e = e0 + s;
    const float* wr = W + (size_t)e * 2048;
    float p[8] = {0, 0, 0, 0, 0, 0, 0, 0};
    for (int k = lane * 4; k < 2048; k += 256) {
      float4 wv = *(const float4*)(wr + k);
#pragma unroll
      for (int b = 0; b < 8; ++b) {
        float4 xv = *(const float4*)(Xs + b * 2048 + k);
        p[b] += wv.x * xv.x + wv.y * xv.y + wv.z * xv.z + wv.w * xv.w;
      }
    }
#pragma unroll
    for (int b = 0; b < 8; ++b)
      for (int m = 1; m < 64; m <<= 1) p[b] += __shfl_xor(p[b], m);
    if (lane == 0) {
      const float bb = bias[e];
#pragma unroll
      for (int b = 0; b < 8; ++b) Y[(size_t)b * 2048 + e] = p[b] + bb;
    }
  }
}

// ---------------------------------------------------------------------------
// 7. KV GEMM: C[16384][4096] = A[16384][2048] @ W[4096][2048]^T + bias
//    bf16 in/out, fp32 accum.  m97 structure: 128x128 tile, BK=32,
//    4 waves each 64x64 (4x4 of 16x16x32 MFMA), global_load_lds width 16.
// ---------------------------------------------------------------------------
__global__ __launch_bounds__(256) void gemm_kv_kernel(
    const unsigned short* __restrict__ A, const unsigned short* __restrict__ W,
    const float* __restrict__ kb, const float* __restrict__ vb,
    unsigned short* __restrict__ C) {
  constexpr int K = 2048;
  __shared__ unsigned short As[128 * 32];
  __shared__ unsigned short Bs[128 * 32];
  const int tid = threadIdx.x;
  const int lane = tid & 63, wave = tid >> 6;
  const int wr = wave >> 1, wc = wave & 1;
  const int bm = blockIdx.x, bn = blockIdx.y;

  // staging: thread t covers tile elems [t*8 .. t*8+7] (row t/4, col (t%4)*8)
  const unsigned short* Ap = A + ((size_t)(bm * 128 + (tid >> 2))) * K + (tid & 3) * 8;
  const unsigned short* Bp = W + ((size_t)(bn * 128 + (tid >> 2))) * K + (tid & 3) * 8;
  unsigned short* lA0 = As + wave * 512;          // round 0 (rows 0..63)
  unsigned short* lA1 = As + 2048 + wave * 512;   // round 1 (rows 64..127)
  unsigned short* lB0 = Bs + wave * 512;
  unsigned short* lB1 = Bs + 2048 + wave * 512;

  f32x4 acc[4][4];
#pragma unroll
  for (int i = 0; i < 4; ++i)
#pragma unroll
    for (int j = 0; j < 4; ++j) acc[i][j] = (f32x4){0.f, 0.f, 0.f, 0.f};

  const unsigned short* aPtr[4];
  const unsigned short* bPtr[4];
#pragma unroll
  for (int mi = 0; mi < 4; ++mi)
    aPtr[mi] = As + (wr * 64 + mi * 16 + (lane & 15)) * 32 + (lane >> 4) * 8;
#pragma unroll
  for (int ni = 0; ni < 4; ++ni)
    bPtr[ni] = Bs + (wc * 64 + ni * 16 + (lane & 15)) * 32 + (lane >> 4) * 8;

  for (int kt = 0; kt < K / 32; ++kt) {
    const int ko = kt * 32;
    gld16(Ap + ko,          lA0);
    gld16(Ap + ko + 64 * K, lA1);
    gld16(Bp + ko,          lB0);
    gld16(Bp + ko + 64 * K, lB1);
    __syncthreads();           // drains vmcnt -> LDS tiles complete
    bf16x8 af[4], bfr[4];
#pragma unroll
    for (int mi = 0; mi < 4; ++mi) af[mi] = *(const bf16x8*)aPtr[mi];
#pragma unroll
    for (int ni = 0; ni < 4; ++ni) bfr[ni] = *(const bf16x8*)bPtr[ni];
#pragma unroll
    for (int mi = 0; mi < 4; ++mi)
#pragma unroll
      for (int ni = 0; ni < 4; ++ni)
        acc[mi][ni] = __builtin_amdgcn_mfma_f32_16x16x32_bf16(af[mi], bfr[ni],
                                                              acc[mi][ni], 0, 0, 0);
    __syncthreads();           // reads done before next stage overwrites
  }

  // epilogue: C/D layout col=lane&15, row=(lane>>4)*4+reg
  const int row0 = bm * 128 + wr * 64;
  const int col0 = bn * 128 + wc * 64;
#pragma unroll
  for (int ni = 0; ni < 4; ++ni) {
    const int col = col0 + ni * 16 + (lane & 15);
    const float bias = (col < 2048) ? kb[col] : vb[col - 2048];
#pragma unroll
    for (int mi = 0; mi < 4; ++mi)
#pragma unroll
      for (int r = 0; r < 4; ++r) {
        const int row = row0 + mi * 16 + (lane >> 4) * 4 + r;
        C[(size_t)row * 4096 + col] = f2bf(acc[mi][ni][r] + bias);
      }
  }
}

// ---------------------------------------------------------------------------
// 8. attention: one block per (b,h). 16-lane d-split per position; RoPE on K;
//    two-pass softmax over S=2048; V accumulate; out / Z.
// ---------------------------------------------------------------------------
__global__ __launch_bounds__(256) void attn_kernel(const unsigned short* __restrict__ KV,
                                                   const float* __restrict__ qv,
                                                   const float* __restrict__ tab,
                                                   float* __restrict__ aout) {
  const int b = blockIdx.x >> 4, h = blockIdx.x & 15;
  const int tid = threadIdx.x, lane = tid & 63, wave = tid >> 6;
  const int seg = lane & 15, rg = lane >> 4;
  __shared__ float sS[2048];
  __shared__ float sRed[8];
  __shared__ float sO[4][128];

  float qf[8];
  {
    const float* qp = qv + (size_t)b * 2048 + h * 128 + seg * 8;
#pragma unroll
    for (int j = 0; j < 8; ++j) qf[j] = qp[j];
  }
  const unsigned short* Kbase = KV + ((size_t)b * 2048) * 4096 + h * 128;
  const unsigned short* Vbase = Kbase + 2048;

  // pass 1: scores
  for (int it = 0; it < 128; ++it) {
    const int t = it * 16 + wave * 4 + rg;
    us8 uv = *(const us8*)(Kbase + (size_t)t * 4096 + seg * 8);
    float k[8];
#pragma unroll
    for (int j = 0; j < 8; ++j) k[j] = bf2f(uv[j]);
    if (seg < 8) {             // RoPE on first 64 dims
#pragma unroll
      for (int p = 0; p < 4; ++p) {
        const int i = seg * 4 + p;
        const float sn = tab[t * 64 + i], cs = tab[t * 64 + 32 + i];
        const float e = k[2 * p], o = k[2 * p + 1];
        k[2 * p]     = e * cs - o * sn;
        k[2 * p + 1] = o * cs + e * sn;
      }
    }
    float part = 0.f;
#pragma unroll
    for (int j = 0; j < 8; ++j) part += qf[j] * k[j];
    part += __shfl_xor(part, 1);
    part += __shfl_xor(part, 2);
    part += __shfl_xor(part, 4);
    part += __shfl_xor(part, 8);
    if (seg == 0) sS[t] = part;
  }
  __syncthreads();

  // softmax (unnormalized; divide by Z at the end)
  float lmax = -3.4e38f;
  for (int t = tid; t < 2048; t += 256) lmax = fmaxf(lmax, sS[t]);
  for (int m = 1; m < 64; m <<= 1) lmax = fmaxf(lmax, __shfl_xor(lmax, m));
  if (lane == 0) sRed[wave] = lmax;
  __syncthreads();
  const float gmax = fmaxf(fmaxf(sRed[0], sRed[1]), fmaxf(sRed[2], sRed[3]));
  float lsum = 0.f;
  for (int t = tid; t < 2048; t += 256) {
    const float e = __expf(sS[t] - gmax);
    sS[t] = e;
    lsum += e;
  }
  for (int m = 1; m < 64; m <<= 1) lsum += __shfl_xor(lsum, m);
  if (lane == 0) sRed[4 + wave] = lsum;
  __syncthreads();
  const float Z = sRed[4] + sRed[5] + sRed[6] + sRed[7];

  // pass 2: V accumulate
  float acc[8] = {0, 0, 0, 0, 0, 0, 0, 0};
  for (int it = 0; it < 128; ++it) {
    const int t = it * 16 + wave * 4 + rg;
    us8 uv = *(const us8*)(Vbase + (size_t)t * 4096 + seg * 8);
    const float p = sS[t];
#pragma unroll
    for (int j = 0; j < 8; ++j) acc[j] += p * bf2f(uv[j]);
  }
#pragma unroll
  for (int j = 0; j < 8; ++j) {
    acc[j] += __shfl_xor(acc[j], 16);
    acc[j] += __shfl_xor(acc[j], 32);
  }
  if (rg == 0) {
#pragma unroll
    for (int j = 0; j < 8; ++j) sO[wave][seg * 8 + j] = acc[j];
  }
  __syncthreads();
  if (tid < 128)
    aout[(size_t)b * 2048 + h * 128 + tid] =
        (sO[0][tid] + sO[1][tid] + sO[2][tid] + sO[3][tid]) / Z;
}

// ---------------------------------------------------------------------------
extern "C" void kernel_launch(void* const* d_in, const int* in_sizes, int n_in,
                              void* d_out, int out_size, void* d_ws, size_t ws_size,
                              hipStream_t stream) {
  (void)in_sizes; (void)n_in; (void)out_size; (void)ws_size;
  const float* hidden = (const float*)d_in[0];
  const int*   ids    = (const int*)d_in[1];
  const float* ln_w   = (const float*)d_in[2];
  const float* ln_b   = (const float*)d_in[3];
  const float* q_w    = (const float*)d_in[4];
  const float* q_b    = (const float*)d_in[5];
  const float* k_w    = (const float*)d_in[6];
  const float* k_b    = (const float*)d_in[7];
  const float* v_w    = (const float*)d_in[8];
  const float* v_b    = (const float*)d_in[9];
  const float* out_w  = (const float*)d_in[10];
  const float* out_b  = (const float*)d_in[11];
  float* out = (float*)d_out;

  char* ws = (char*)d_ws;
  unsigned short* hs  = (unsigned short*)ws; ws += (size_t)16384 * 2048 * 2;  // 64 MB
  unsigned short* Wkv = (unsigned short*)ws; ws += (size_t)4096 * 2048 * 2;   // 16 MB
  unsigned short* KV  = (unsigned short*)ws; ws += (size_t)16384 * 4096 * 2;  // 128 MB
  float* sctab = (float*)ws; ws += (size_t)2048 * 64 * 4;                     // 512 KB
  float* qv    = (float*)ws; ws += (size_t)8 * 2048 * 4;
  float* hl    = (float*)ws; ws += (size_t)8 * 2048 * 4;
  float* aout  = (float*)ws; ws += (size_t)8 * 2048 * 4;
  int*   ixp   = (int*)ws;   ws += 256;

  ix_kernel<<<8, 256, 0, stream>>>(ids, ixp);
  ln_kernel<<<16384, 256, 0, stream>>>(hidden, ln_w, ln_b, hs);
  f2bf_kernel<<<4096, 256, 0, stream>>>(k_w, Wkv);
  f2bf_kernel<<<4096, 256, 0, stream>>>(v_w, Wkv + (size_t)2048 * 2048);
  sctab_kernel<<<2048, 64, 0, stream>>>(sctab);
  hlast_kernel<<<8, 256, 0, stream>>>(hidden, ln_w, ln_b, ixp, hl);
  gemv8_kernel<<<32, 256, 0, stream>>>(hl, q_w, q_b, qv);
  gemm_kv_kernel<<<dim3(128, 32), 256, 0, stream>>>(hs, Wkv, k_b, v_b, KV);
  attn_kernel<<<128, 256, 0, stream>>>(KV, qv, sctab, aout);
  gemv8_kernel<<<32, 256, 0, stream>>>(aout, out_w, out_b, out);
}

// Round 2
// 646.063 us; speedup vs baseline: 1.3411x; 1.3411x over previous
//
#include <hip/hip_runtime.h>
#include <hip/hip_bf16.h>
#include <cstdint>
#include <cstddef>

// ---------------------------------------------------------------------------
// NostARHeadAttention: LN -> {Q(last), K, V} proj -> RoPE(K) -> 1-query attn
// -> out proj.  B=8, S=2048, E=2048, H=16, D=128, ROT=64, PAD=50257.
// R1: parallelized GEMV (512 blocks, 1 output/wave) and attention
// (score/out/fin 3-kernel split, 1024/512/128 blocks) — R0 versions were
// latency-bound at 32/128 blocks.  GEMM unchanged (m97 plateau, 34% MfmaUtil).
// ---------------------------------------------------------------------------

using bf16x8 = __attribute__((ext_vector_type(8))) __bf16;
using f32x4  = __attribute__((ext_vector_type(4))) float;
using us8    = __attribute__((ext_vector_type(8))) unsigned short;

__device__ __forceinline__ float bf2f(unsigned short u) {
  return __uint_as_float(((unsigned)u) << 16);
}
__device__ __forceinline__ unsigned short f2bf(float f) {
  unsigned u = __float_as_uint(f);
  u += 0x7fffu + ((u >> 16) & 1u);   // RNE
  return (unsigned short)(u >> 16);
}

__device__ __forceinline__ void gld16(const void* g, void* l) {
  __builtin_amdgcn_global_load_lds((__attribute__((address_space(1))) void*)g,
                                   (__attribute__((address_space(3))) void*)l,
                                   16, 0, 0);
}

// ---------------------------------------------------------------------------
// 1. last non-pad index per batch
// ---------------------------------------------------------------------------
__global__ __launch_bounds__(256) void ix_kernel(const int* __restrict__ ids,
                                                 int* __restrict__ ixp) {
  const int b = blockIdx.x, tid = threadIdx.x;
  int best = -1;
  for (int t = tid; t < 2048; t += 256)
    if (ids[b * 2048 + t] != 50257) best = (t > best) ? t : best;
  for (int m = 1; m < 64; m <<= 1) {
    int o = __shfl_xor(best, m);
    best = (o > best) ? o : best;
  }
  __shared__ int rb[4];
  if ((tid & 63) == 0) rb[tid >> 6] = best;
  __syncthreads();
  if (tid == 0) {
    int r = rb[0];
    for (int w = 1; w < 4; ++w) r = (rb[w] > r) ? rb[w] : r;
    ixp[b] = (r < 0) ? 0 : r;
  }
}

// ---------------------------------------------------------------------------
// 2. LayerNorm all rows -> bf16
// ---------------------------------------------------------------------------
__global__ __launch_bounds__(256) void ln_kernel(const float* __restrict__ x,
                                                 const float* __restrict__ gw,
                                                 const float* __restrict__ gb,
                                                 unsigned short* __restrict__ y) {
  const size_t row = blockIdx.x;
  const float* xr = x + row * 2048;
  const int tid = threadIdx.x;
  float4 a = ((const float4*)xr)[tid];
  float4 b = ((const float4*)xr)[tid + 256];
  float s  = a.x + a.y + a.z + a.w + b.x + b.y + b.z + b.w;
  float ss = a.x*a.x + a.y*a.y + a.z*a.z + a.w*a.w +
             b.x*b.x + b.y*b.y + b.z*b.z + b.w*b.w;
  for (int m = 1; m < 64; m <<= 1) { s += __shfl_xor(s, m); ss += __shfl_xor(ss, m); }
  __shared__ float rs[4], rss[4];
  const int wave = tid >> 6, lane = tid & 63;
  if (lane == 0) { rs[wave] = s; rss[wave] = ss; }
  __syncthreads();
  s  = rs[0] + rs[1] + rs[2] + rs[3];
  ss = rss[0] + rss[1] + rss[2] + rss[3];
  const float mu = s * (1.f / 2048.f);
  const float var = ss * (1.f / 2048.f) - mu * mu;
  const float r = rsqrtf(var + 1e-5f);
  unsigned short o[8];
  const int i0 = tid * 4, i1 = 1024 + tid * 4;
  o[0] = f2bf((a.x - mu) * r * gw[i0 + 0] + gb[i0 + 0]);
  o[1] = f2bf((a.y - mu) * r * gw[i0 + 1] + gb[i0 + 1]);
  o[2] = f2bf((a.z - mu) * r * gw[i0 + 2] + gb[i0 + 2]);
  o[3] = f2bf((a.w - mu) * r * gw[i0 + 3] + gb[i0 + 3]);
  o[4] = f2bf((b.x - mu) * r * gw[i1 + 0] + gb[i1 + 0]);
  o[5] = f2bf((b.y - mu) * r * gw[i1 + 1] + gb[i1 + 1]);
  o[6] = f2bf((b.z - mu) * r * gw[i1 + 2] + gb[i1 + 2]);
  o[7] = f2bf((b.w - mu) * r * gw[i1 + 3] + gb[i1 + 3]);
  ushort4 p0 = {o[0], o[1], o[2], o[3]};
  ushort4 p1 = {o[4], o[5], o[6], o[7]};
  *(ushort4*)(y + row * 2048 + i0) = p0;
  *(ushort4*)(y + row * 2048 + i1) = p1;
}

// ---------------------------------------------------------------------------
// 3. fp32 -> bf16 weight convert
// ---------------------------------------------------------------------------
__global__ __launch_bounds__(256) void f2bf_kernel(const float* __restrict__ src,
                                                   unsigned short* __restrict__ dst) {
  const size_t i = (size_t)blockIdx.x * 256 + threadIdx.x;
  float4 v = ((const float4*)src)[i];
  ushort4 o = {f2bf(v.x), f2bf(v.y), f2bf(v.z), f2bf(v.w)};
  ((ushort4*)dst)[i] = o;
}

// ---------------------------------------------------------------------------
// 4. sin/cos table
// ---------------------------------------------------------------------------
__global__ void sctab_kernel(float* __restrict__ tab) {
  const int t = blockIdx.x, tid = threadIdx.x;
  const int i = tid & 31;
  const float inv = powf(10000.f, -(float)i / 32.f);
  const float ang = (float)t * inv;
  tab[t * 64 + tid] = (tid < 32) ? sinf(ang) : cosf(ang);
}

// ---------------------------------------------------------------------------
// 5. LN of last-token row per batch -> fp32
// ---------------------------------------------------------------------------
__global__ __launch_bounds__(256) void hlast_kernel(const float* __restrict__ x,
                                                    const float* __restrict__ gw,
                                                    const float* __restrict__ gb,
                                                    const int* __restrict__ ixp,
                                                    float* __restrict__ hl) {
  const int b = blockIdx.x;
  const size_t row = (size_t)b * 2048 + ixp[b];
  const float* xr = x + row * 2048;
  const int tid = threadIdx.x;
  float4 a = ((const float4*)xr)[tid];
  float4 c = ((const float4*)xr)[tid + 256];
  float s  = a.x + a.y + a.z + a.w + c.x + c.y + c.z + c.w;
  float ss = a.x*a.x + a.y*a.y + a.z*a.z + a.w*a.w +
             c.x*c.x + c.y*c.y + c.z*c.z + c.w*c.w;
  for (int m = 1; m < 64; m <<= 1) { s += __shfl_xor(s, m); ss += __shfl_xor(ss, m); }
  __shared__ float rs[4], rss[4];
  const int wave = tid >> 6, lane = tid & 63;
  if (lane == 0) { rs[wave] = s; rss[wave] = ss; }
  __syncthreads();
  s  = rs[0] + rs[1] + rs[2] + rs[3];
  ss = rss[0] + rss[1] + rss[2] + rss[3];
  const float mu = s * (1.f / 2048.f);
  const float var = ss * (1.f / 2048.f) - mu * mu;
  const float r = rsqrtf(var + 1e-5f);
  const int i0 = tid * 4, i1 = 1024 + tid * 4;
  float* yo = hl + (size_t)b * 2048;
  yo[i0 + 0] = (a.x - mu) * r * gw[i0 + 0] + gb[i0 + 0];
  yo[i0 + 1] = (a.y - mu) * r * gw[i0 + 1] + gb[i0 + 1];
  yo[i0 + 2] = (a.z - mu) * r * gw[i0 + 2] + gb[i0 + 2];
  yo[i0 + 3] = (a.w - mu) * r * gw[i0 + 3] + gb[i0 + 3];
  yo[i1 + 0] = (c.x - mu) * r * gw[i1 + 0] + gb[i1 + 0];
  yo[i1 + 1] = (c.y - mu) * r * gw[i1 + 1] + gb[i1 + 1];
  yo[i1 + 2] = (c.z - mu) * r * gw[i1 + 2] + gb[i1 + 2];
  yo[i1 + 3] = (c.w - mu) * r * gw[i1 + 3] + gb[i1 + 3];
}

// ---------------------------------------------------------------------------
// 6. GEMV: Y[8][2048] = X[8][2048] @ W^T + bias (fp32).
//    R1: 512 blocks x 4 waves, ONE output per wave, K split over 64 lanes.
//    X (64 KB) stays L1/L2-hot; W rows read coalesced 1 KB/wave/iter.
// ---------------------------------------------------------------------------
__global__ __launch_bounds__(256) void gemv8_kernel(const float* __restrict__ X,
                                                    const float* __restrict__ W,
                                                    const float* __restrict__ bias,
                                                    float* __restrict__ Y) {
  const int tid = threadIdx.x, lane = tid & 63, wave = tid >> 6;
  const int e = blockIdx.x * 4 + wave;
  const float* wr = W + (size_t)e * 2048;
  float p[8] = {0, 0, 0, 0, 0, 0, 0, 0};
#pragma unroll
  for (int it = 0; it < 8; ++it) {
    const int k = it * 256 + lane * 4;
    float4 wv = *(const float4*)(wr + k);
#pragma unroll
    for (int b = 0; b < 8; ++b) {
      float4 xv = *(const float4*)(X + b * 2048 + k);
      p[b] += wv.x * xv.x + wv.y * xv.y + wv.z * xv.z + wv.w * xv.w;
    }
  }
#pragma unroll
  for (int b = 0; b < 8; ++b)
    for (int m = 1; m < 64; m <<= 1) p[b] += __shfl_xor(p[b], m);
  if (lane == 0) {
    const float bb = bias[e];
#pragma unroll
    for (int b = 0; b < 8; ++b) Y[(size_t)b * 2048 + e] = p[b] + bb;
  }
}

// ---------------------------------------------------------------------------
// 7. KV GEMM (unchanged m97 structure): C[16384][4096] = A @ W^T + bias
// ---------------------------------------------------------------------------
__global__ __launch_bounds__(256) void gemm_kv_kernel(
    const unsigned short* __restrict__ A, const unsigned short* __restrict__ W,
    const float* __restrict__ kb, const float* __restrict__ vb,
    unsigned short* __restrict__ C) {
  constexpr int K = 2048;
  __shared__ unsigned short As[128 * 32];
  __shared__ unsigned short Bs[128 * 32];
  const int tid = threadIdx.x;
  const int lane = tid & 63, wave = tid >> 6;
  const int wr = wave >> 1, wc = wave & 1;
  const int bm = blockIdx.x, bn = blockIdx.y;

  const unsigned short* Ap = A + ((size_t)(bm * 128 + (tid >> 2))) * K + (tid & 3) * 8;
  const unsigned short* Bp = W + ((size_t)(bn * 128 + (tid >> 2))) * K + (tid & 3) * 8;
  unsigned short* lA0 = As + wave * 512;
  unsigned short* lA1 = As + 2048 + wave * 512;
  unsigned short* lB0 = Bs + wave * 512;
  unsigned short* lB1 = Bs + 2048 + wave * 512;

  f32x4 acc[4][4];
#pragma unroll
  for (int i = 0; i < 4; ++i)
#pragma unroll
    for (int j = 0; j < 4; ++j) acc[i][j] = (f32x4){0.f, 0.f, 0.f, 0.f};

  const unsigned short* aPtr[4];
  const unsigned short* bPtr[4];
#pragma unroll
  for (int mi = 0; mi < 4; ++mi)
    aPtr[mi] = As + (wr * 64 + mi * 16 + (lane & 15)) * 32 + (lane >> 4) * 8;
#pragma unroll
  for (int ni = 0; ni < 4; ++ni)
    bPtr[ni] = Bs + (wc * 64 + ni * 16 + (lane & 15)) * 32 + (lane >> 4) * 8;

  for (int kt = 0; kt < K / 32; ++kt) {
    const int ko = kt * 32;
    gld16(Ap + ko,          lA0);
    gld16(Ap + ko + 64 * K, lA1);
    gld16(Bp + ko,          lB0);
    gld16(Bp + ko + 64 * K, lB1);
    __syncthreads();
    bf16x8 af[4], bfr[4];
#pragma unroll
    for (int mi = 0; mi < 4; ++mi) af[mi] = *(const bf16x8*)aPtr[mi];
#pragma unroll
    for (int ni = 0; ni < 4; ++ni) bfr[ni] = *(const bf16x8*)bPtr[ni];
#pragma unroll
    for (int mi = 0; mi < 4; ++mi)
#pragma unroll
      for (int ni = 0; ni < 4; ++ni)
        acc[mi][ni] = __builtin_amdgcn_mfma_f32_16x16x32_bf16(af[mi], bfr[ni],
                                                              acc[mi][ni], 0, 0, 0);
    __syncthreads();
  }

  const int row0 = bm * 128 + wr * 64;
  const int col0 = bn * 128 + wc * 64;
#pragma unroll
  for (int ni = 0; ni < 4; ++ni) {
    const int col = col0 + ni * 16 + (lane & 15);
    const float bias = (col < 2048) ? kb[col] : vb[col - 2048];
#pragma unroll
    for (int mi = 0; mi < 4; ++mi)
#pragma unroll
      for (int r = 0; r < 4; ++r) {
        const int row = row0 + mi * 16 + (lane >> 4) * 4 + r;
        C[(size_t)row * 4096 + col] = f2bf(acc[mi][ni][r] + bias);
      }
  }
}

// ---------------------------------------------------------------------------
// 8a. attn_score: 1024 blocks = (b,h) x 8 chunks of 256 positions.
//     Per position: RoPE(K) . q -> scores[] global; per-chunk max -> gmaxp[].
// ---------------------------------------------------------------------------
__global__ __launch_bounds__(256) void attn_score_kernel(
    const unsigned short* __restrict__ KV, const float* __restrict__ qv,
    const float* __restrict__ tab, float* __restrict__ scores,
    float* __restrict__ gmaxp) {
  const int bh = blockIdx.x >> 3, chunk = blockIdx.x & 7;
  const int b = bh >> 4, h = bh & 15;
  const int tid = threadIdx.x, lane = tid & 63, wave = tid >> 6;
  const int seg = lane & 15, rg = lane >> 4;
  const int t0 = chunk * 256;

  float qf[8];
  {
    const float* qp = qv + (size_t)bh * 128 + seg * 8;
#pragma unroll
    for (int j = 0; j < 8; ++j) qf[j] = qp[j];
  }
  const unsigned short* Kbase = KV + ((size_t)b * 2048) * 4096 + h * 128;

  float lmax = -3.4e38f;
  for (int it = 0; it < 16; ++it) {
    const int t = t0 + it * 16 + wave * 4 + rg;
    us8 uv = *(const us8*)(Kbase + (size_t)t * 4096 + seg * 8);
    float k[8];
#pragma unroll
    for (int j = 0; j < 8; ++j) k[j] = bf2f(uv[j]);
    if (seg < 8) {
#pragma unroll
      for (int p = 0; p < 4; ++p) {
        const int i = seg * 4 + p;
        const float sn = tab[t * 64 + i], cs = tab[t * 64 + 32 + i];
        const float e = k[2 * p], o = k[2 * p + 1];
        k[2 * p]     = e * cs - o * sn;
        k[2 * p + 1] = o * cs + e * sn;
      }
    }
    float part = 0.f;
#pragma unroll
    for (int j = 0; j < 8; ++j) part += qf[j] * k[j];
    part += __shfl_xor(part, 1);
    part += __shfl_xor(part, 2);
    part += __shfl_xor(part, 4);
    part += __shfl_xor(part, 8);
    if (seg == 0) scores[(size_t)bh * 2048 + t] = part;
    lmax = fmaxf(lmax, part);
  }
  for (int m = 1; m < 64; m <<= 1) lmax = fmaxf(lmax, __shfl_xor(lmax, m));
  __shared__ float rmax[4];
  if (lane == 0) rmax[wave] = lmax;
  __syncthreads();
  if (tid == 0)
    gmaxp[blockIdx.x] = fmaxf(fmaxf(rmax[0], rmax[1]), fmaxf(rmax[2], rmax[3]));
}

// ---------------------------------------------------------------------------
// 8b. attn_out: 512 blocks = (b,h) x 4 chunks of 512 positions.
//     p = exp(score - gmax); partial V-accumulate + partial Z (no atomics).
// ---------------------------------------------------------------------------
__global__ __launch_bounds__(256) void attn_out_kernel(
    const unsigned short* __restrict__ KV, const float* __restrict__ scores,
    const float* __restrict__ gmaxp, float* __restrict__ paout,
    float* __restrict__ pZ) {
  const int bh = blockIdx.x >> 2, c = blockIdx.x & 3;
  const int b = bh >> 4, h = bh & 15;
  const int tid = threadIdx.x, lane = tid & 63, wave = tid >> 6;
  const int seg = lane & 15, rg = lane >> 4;
  const int t0 = c * 512;

  float gmax = -3.4e38f;
#pragma unroll
  for (int i = 0; i < 8; ++i) gmax = fmaxf(gmax, gmaxp[bh * 8 + i]);

  const unsigned short* Vbase = KV + ((size_t)b * 2048) * 4096 + h * 128 + 2048;
  float acc[8] = {0, 0, 0, 0, 0, 0, 0, 0};
  float lsum = 0.f;
  for (int it = 0; it < 32; ++it) {
    const int t = t0 + it * 16 + wave * 4 + rg;
    const float p = __expf(scores[(size_t)bh * 2048 + t] - gmax);
    us8 uv = *(const us8*)(Vbase + (size_t)t * 4096 + seg * 8);
#pragma unroll
    for (int j = 0; j < 8; ++j) acc[j] += p * bf2f(uv[j]);
    if (seg == 0) lsum += p;
  }
#pragma unroll
  for (int j = 0; j < 8; ++j) {
    acc[j] += __shfl_xor(acc[j], 16);
    acc[j] += __shfl_xor(acc[j], 32);
  }
  for (int m = 1; m < 64; m <<= 1) lsum += __shfl_xor(lsum, m);

  __shared__ float sO[4][128];
  __shared__ float sZ[4];
  if (rg == 0) {
#pragma unroll
    for (int j = 0; j < 8; ++j) sO[wave][seg * 8 + j] = acc[j];
  }
  if (lane == 0) sZ[wave] = lsum;
  __syncthreads();
  if (tid < 128)
    paout[(size_t)blockIdx.x * 128 + tid] =
        sO[0][tid] + sO[1][tid] + sO[2][tid] + sO[3][tid];
  if (tid == 128) pZ[blockIdx.x] = sZ[0] + sZ[1] + sZ[2] + sZ[3];
}

// ---------------------------------------------------------------------------
// 8c. attn_fin: combine 4 partials per (b,h), divide by Z.
// ---------------------------------------------------------------------------
__global__ __launch_bounds__(128) void attn_fin_kernel(
    const float* __restrict__ paout, const float* __restrict__ pZ,
    float* __restrict__ aout) {
  const int bh = blockIdx.x, d = threadIdx.x;
  const float Z = pZ[bh * 4 + 0] + pZ[bh * 4 + 1] + pZ[bh * 4 + 2] + pZ[bh * 4 + 3];
  const float s = paout[(size_t)(bh * 4 + 0) * 128 + d] +
                  paout[(size_t)(bh * 4 + 1) * 128 + d] +
                  paout[(size_t)(bh * 4 + 2) * 128 + d] +
                  paout[(size_t)(bh * 4 + 3) * 128 + d];
  aout[(size_t)bh * 128 + d] = s / Z;
}

// ---------------------------------------------------------------------------
extern "C" void kernel_launch(void* const* d_in, const int* in_sizes, int n_in,
                              void* d_out, int out_size, void* d_ws, size_t ws_size,
                              hipStream_t stream) {
  (void)in_sizes; (void)n_in; (void)out_size; (void)ws_size;
  const float* hidden = (const float*)d_in[0];
  const int*   ids    = (const int*)d_in[1];
  const float* ln_w   = (const float*)d_in[2];
  const float* ln_b   = (const float*)d_in[3];
  const float* q_w    = (const float*)d_in[4];
  const float* q_b    = (const float*)d_in[5];
  const float* k_w    = (const float*)d_in[6];
  const float* k_b    = (const float*)d_in[7];
  const float* v_w    = (const float*)d_in[8];
  const float* v_b    = (const float*)d_in[9];
  const float* out_w  = (const float*)d_in[10];
  const float* out_b  = (const float*)d_in[11];
  float* out = (float*)d_out;

  char* ws = (char*)d_ws;
  unsigned short* hs  = (unsigned short*)ws; ws += (size_t)16384 * 2048 * 2;  // 64 MB
  unsigned short* Wkv = (unsigned short*)ws; ws += (size_t)4096 * 2048 * 2;   // 16 MB
  unsigned short* KV  = (unsigned short*)ws; ws += (size_t)16384 * 4096 * 2;  // 128 MB
  float* sctab  = (float*)ws; ws += (size_t)2048 * 64 * 4;                    // 512 KB
  float* qv     = (float*)ws; ws += (size_t)8 * 2048 * 4;
  float* hl     = (float*)ws; ws += (size_t)8 * 2048 * 4;
  float* aout   = (float*)ws; ws += (size_t)8 * 2048 * 4;
  float* scores = (float*)ws; ws += (size_t)128 * 2048 * 4;                   // 1 MB
  float* gmaxp  = (float*)ws; ws += 1024 * 4;
  float* paout  = (float*)ws; ws += (size_t)512 * 128 * 4;                    // 256 KB
  float* pZ     = (float*)ws; ws += 512 * 4;
  int*   ixp    = (int*)ws;  ws += 256;

  ix_kernel<<<8, 256, 0, stream>>>(ids, ixp);
  ln_kernel<<<16384, 256, 0, stream>>>(hidden, ln_w, ln_b, hs);
  f2bf_kernel<<<4096, 256, 0, stream>>>(k_w, Wkv);
  f2bf_kernel<<<4096, 256, 0, stream>>>(v_w, Wkv + (size_t)2048 * 2048);
  sctab_kernel<<<2048, 64, 0, stream>>>(sctab);
  hlast_kernel<<<8, 256, 0, stream>>>(hidden, ln_w, ln_b, ixp, hl);
  gemv8_kernel<<<512, 256, 0, stream>>>(hl, q_w, q_b, qv);
  gemm_kv_kernel<<<dim3(128, 32), 256, 0, stream>>>(hs, Wkv, k_b, v_b, KV);
  attn_score_kernel<<<1024, 256, 0, stream>>>(KV, qv, sctab, scores, gmaxp);
  attn_out_kernel<<<512, 256, 0, stream>>>(KV, scores, gmaxp, paout, pZ);
  attn_fin_kernel<<<128, 128, 0, stream>>>(paout, pZ, aout);
  gemv8_kernel<<<512, 256, 0, stream>>>(aout, out_w, out_b, out);
}

// Round 3
// 536.187 us; speedup vs baseline: 1.6159x; 1.2049x over previous
//
#include <hip/hip_runtime.h>
#include <hip/hip_bf16.h>
#include <cstdint>
#include <cstddef>

// ---------------------------------------------------------------------------
// NostARHeadAttention: LN -> {Q(last), K} proj -> RoPE(K) -> 1-query attn
// with V-elimination: out_head = v_w_head @ (softmax-weighted sum of hs) + v_b.
// B=8, S=2048, E=2048, H=16, D=128, ROT=64, PAD=50257.
// R2: dropped V projection entirely (halves the MFMA GEMM); added
// attn_z / attn_wsum / attn_comb / attn_vgemv chain.
// ---------------------------------------------------------------------------

using bf16x8 = __attribute__((ext_vector_type(8))) __bf16;
using f32x4  = __attribute__((ext_vector_type(4))) float;
using us8    = __attribute__((ext_vector_type(8))) unsigned short;

__device__ __forceinline__ float bf2f(unsigned short u) {
  return __uint_as_float(((unsigned)u) << 16);
}
__device__ __forceinline__ unsigned short f2bf(float f) {
  unsigned u = __float_as_uint(f);
  u += 0x7fffu + ((u >> 16) & 1u);   // RNE
  return (unsigned short)(u >> 16);
}

__device__ __forceinline__ void gld16(const void* g, void* l) {
  __builtin_amdgcn_global_load_lds((__attribute__((address_space(1))) void*)g,
                                   (__attribute__((address_space(3))) void*)l,
                                   16, 0, 0);
}

// ---------------------------------------------------------------------------
// 1. last non-pad index per batch
// ---------------------------------------------------------------------------
__global__ __launch_bounds__(256) void ix_kernel(const int* __restrict__ ids,
                                                 int* __restrict__ ixp) {
  const int b = blockIdx.x, tid = threadIdx.x;
  int best = -1;
  for (int t = tid; t < 2048; t += 256)
    if (ids[b * 2048 + t] != 50257) best = (t > best) ? t : best;
  for (int m = 1; m < 64; m <<= 1) {
    int o = __shfl_xor(best, m);
    best = (o > best) ? o : best;
  }
  __shared__ int rb[4];
  if ((tid & 63) == 0) rb[tid >> 6] = best;
  __syncthreads();
  if (tid == 0) {
    int r = rb[0];
    for (int w = 1; w < 4; ++w) r = (rb[w] > r) ? rb[w] : r;
    ixp[b] = (r < 0) ? 0 : r;
  }
}

// ---------------------------------------------------------------------------
// 2. LayerNorm all rows -> bf16
// ---------------------------------------------------------------------------
__global__ __launch_bounds__(256) void ln_kernel(const float* __restrict__ x,
                                                 const float* __restrict__ gw,
                                                 const float* __restrict__ gb,
                                                 unsigned short* __restrict__ y) {
  const size_t row = blockIdx.x;
  const float* xr = x + row * 2048;
  const int tid = threadIdx.x;
  float4 a = ((const float4*)xr)[tid];
  float4 b = ((const float4*)xr)[tid + 256];
  float s  = a.x + a.y + a.z + a.w + b.x + b.y + b.z + b.w;
  float ss = a.x*a.x + a.y*a.y + a.z*a.z + a.w*a.w +
             b.x*b.x + b.y*b.y + b.z*b.z + b.w*b.w;
  for (int m = 1; m < 64; m <<= 1) { s += __shfl_xor(s, m); ss += __shfl_xor(ss, m); }
  __shared__ float rs[4], rss[4];
  const int wave = tid >> 6, lane = tid & 63;
  if (lane == 0) { rs[wave] = s; rss[wave] = ss; }
  __syncthreads();
  s  = rs[0] + rs[1] + rs[2] + rs[3];
  ss = rss[0] + rss[1] + rss[2] + rss[3];
  const float mu = s * (1.f / 2048.f);
  const float var = ss * (1.f / 2048.f) - mu * mu;
  const float r = rsqrtf(var + 1e-5f);
  unsigned short o[8];
  const int i0 = tid * 4, i1 = 1024 + tid * 4;
  o[0] = f2bf((a.x - mu) * r * gw[i0 + 0] + gb[i0 + 0]);
  o[1] = f2bf((a.y - mu) * r * gw[i0 + 1] + gb[i0 + 1]);
  o[2] = f2bf((a.z - mu) * r * gw[i0 + 2] + gb[i0 + 2]);
  o[3] = f2bf((a.w - mu) * r * gw[i0 + 3] + gb[i0 + 3]);
  o[4] = f2bf((b.x - mu) * r * gw[i1 + 0] + gb[i1 + 0]);
  o[5] = f2bf((b.y - mu) * r * gw[i1 + 1] + gb[i1 + 1]);
  o[6] = f2bf((b.z - mu) * r * gw[i1 + 2] + gb[i1 + 2]);
  o[7] = f2bf((b.w - mu) * r * gw[i1 + 3] + gb[i1 + 3]);
  ushort4 p0 = {o[0], o[1], o[2], o[3]};
  ushort4 p1 = {o[4], o[5], o[6], o[7]};
  *(ushort4*)(y + row * 2048 + i0) = p0;
  *(ushort4*)(y + row * 2048 + i1) = p1;
}

// ---------------------------------------------------------------------------
// 3. fp32 -> bf16 weight convert (k_w only now)
// ---------------------------------------------------------------------------
__global__ __launch_bounds__(256) void f2bf_kernel(const float* __restrict__ src,
                                                   unsigned short* __restrict__ dst) {
  const size_t i = (size_t)blockIdx.x * 256 + threadIdx.x;
  float4 v = ((const float4*)src)[i];
  ushort4 o = {f2bf(v.x), f2bf(v.y), f2bf(v.z), f2bf(v.w)};
  ((ushort4*)dst)[i] = o;
}

// ---------------------------------------------------------------------------
// 4. sin/cos table
// ---------------------------------------------------------------------------
__global__ void sctab_kernel(float* __restrict__ tab) {
  const int t = blockIdx.x, tid = threadIdx.x;
  const int i = tid & 31;
  const float inv = powf(10000.f, -(float)i / 32.f);
  const float ang = (float)t * inv;
  tab[t * 64 + tid] = (tid < 32) ? sinf(ang) : cosf(ang);
}

// ---------------------------------------------------------------------------
// 5. LN of last-token row per batch -> fp32
// ---------------------------------------------------------------------------
__global__ __launch_bounds__(256) void hlast_kernel(const float* __restrict__ x,
                                                    const float* __restrict__ gw,
                                                    const float* __restrict__ gb,
                                                    const int* __restrict__ ixp,
                                                    float* __restrict__ hl) {
  const int b = blockIdx.x;
  const size_t row = (size_t)b * 2048 + ixp[b];
  const float* xr = x + row * 2048;
  const int tid = threadIdx.x;
  float4 a = ((const float4*)xr)[tid];
  float4 c = ((const float4*)xr)[tid + 256];
  float s  = a.x + a.y + a.z + a.w + c.x + c.y + c.z + c.w;
  float ss = a.x*a.x + a.y*a.y + a.z*a.z + a.w*a.w +
             c.x*c.x + c.y*c.y + c.z*c.z + c.w*c.w;
  for (int m = 1; m < 64; m <<= 1) { s += __shfl_xor(s, m); ss += __shfl_xor(ss, m); }
  __shared__ float rs[4], rss[4];
  const int wave = tid >> 6, lane = tid & 63;
  if (lane == 0) { rs[wave] = s; rss[wave] = ss; }
  __syncthreads();
  s  = rs[0] + rs[1] + rs[2] + rs[3];
  ss = rss[0] + rss[1] + rss[2] + rss[3];
  const float mu = s * (1.f / 2048.f);
  const float var = ss * (1.f / 2048.f) - mu * mu;
  const float r = rsqrtf(var + 1e-5f);
  const int i0 = tid * 4, i1 = 1024 + tid * 4;
  float* yo = hl + (size_t)b * 2048;
  yo[i0 + 0] = (a.x - mu) * r * gw[i0 + 0] + gb[i0 + 0];
  yo[i0 + 1] = (a.y - mu) * r * gw[i0 + 1] + gb[i0 + 1];
  yo[i0 + 2] = (a.z - mu) * r * gw[i0 + 2] + gb[i0 + 2];
  yo[i0 + 3] = (a.w - mu) * r * gw[i0 + 3] + gb[i0 + 3];
  yo[i1 + 0] = (c.x - mu) * r * gw[i1 + 0] + gb[i1 + 0];
  yo[i1 + 1] = (c.y - mu) * r * gw[i1 + 1] + gb[i1 + 1];
  yo[i1 + 2] = (c.z - mu) * r * gw[i1 + 2] + gb[i1 + 2];
  yo[i1 + 3] = (c.w - mu) * r * gw[i1 + 3] + gb[i1 + 3];
}

// ---------------------------------------------------------------------------
// 6. GEMV: Y[8][2048] = X[8][2048] @ W^T + bias (fp32), 512 blocks.
// ---------------------------------------------------------------------------
__global__ __launch_bounds__(256) void gemv8_kernel(const float* __restrict__ X,
                                                    const float* __restrict__ W,
                                                    const float* __restrict__ bias,
                                                    float* __restrict__ Y) {
  const int tid = threadIdx.x, lane = tid & 63, wave = tid >> 6;
  const int e = blockIdx.x * 4 + wave;
  const float* wr = W + (size_t)e * 2048;
  float p[8] = {0, 0, 0, 0, 0, 0, 0, 0};
#pragma unroll
  for (int it = 0; it < 8; ++it) {
    const int k = it * 256 + lane * 4;
    float4 wv = *(const float4*)(wr + k);
#pragma unroll
    for (int b = 0; b < 8; ++b) {
      float4 xv = *(const float4*)(X + b * 2048 + k);
      p[b] += wv.x * xv.x + wv.y * xv.y + wv.z * xv.z + wv.w * xv.w;
    }
  }
#pragma unroll
  for (int b = 0; b < 8; ++b)
    for (int m = 1; m < 64; m <<= 1) p[b] += __shfl_xor(p[b], m);
  if (lane == 0) {
    const float bb = bias[e];
#pragma unroll
    for (int b = 0; b < 8; ++b) Y[(size_t)b * 2048 + e] = p[b] + bb;
  }
}

// ---------------------------------------------------------------------------
// 7. K GEMM (m97 structure): Kout[16384][2048] = hs @ k_w^T + k_b, bf16.
// ---------------------------------------------------------------------------
__global__ __launch_bounds__(256) void gemm_k_kernel(
    const unsigned short* __restrict__ A, const unsigned short* __restrict__ W,
    const float* __restrict__ kb, unsigned short* __restrict__ C) {
  constexpr int K = 2048;
  __shared__ unsigned short As[128 * 32];
  __shared__ unsigned short Bs[128 * 32];
  const int tid = threadIdx.x;
  const int lane = tid & 63, wave = tid >> 6;
  const int wr = wave >> 1, wc = wave & 1;
  const int bm = blockIdx.x, bn = blockIdx.y;

  const unsigned short* Ap = A + ((size_t)(bm * 128 + (tid >> 2))) * K + (tid & 3) * 8;
  const unsigned short* Bp = W + ((size_t)(bn * 128 + (tid >> 2))) * K + (tid & 3) * 8;
  unsigned short* lA0 = As + wave * 512;
  unsigned short* lA1 = As + 2048 + wave * 512;
  unsigned short* lB0 = Bs + wave * 512;
  unsigned short* lB1 = Bs + 2048 + wave * 512;

  f32x4 acc[4][4];
#pragma unroll
  for (int i = 0; i < 4; ++i)
#pragma unroll
    for (int j = 0; j < 4; ++j) acc[i][j] = (f32x4){0.f, 0.f, 0.f, 0.f};

  const unsigned short* aPtr[4];
  const unsigned short* bPtr[4];
#pragma unroll
  for (int mi = 0; mi < 4; ++mi)
    aPtr[mi] = As + (wr * 64 + mi * 16 + (lane & 15)) * 32 + (lane >> 4) * 8;
#pragma unroll
  for (int ni = 0; ni < 4; ++ni)
    bPtr[ni] = Bs + (wc * 64 + ni * 16 + (lane & 15)) * 32 + (lane >> 4) * 8;

  for (int kt = 0; kt < K / 32; ++kt) {
    const int ko = kt * 32;
    gld16(Ap + ko,          lA0);
    gld16(Ap + ko + 64 * K, lA1);
    gld16(Bp + ko,          lB0);
    gld16(Bp + ko + 64 * K, lB1);
    __syncthreads();
    bf16x8 af[4], bfr[4];
#pragma unroll
    for (int mi = 0; mi < 4; ++mi) af[mi] = *(const bf16x8*)aPtr[mi];
#pragma unroll
    for (int ni = 0; ni < 4; ++ni) bfr[ni] = *(const bf16x8*)bPtr[ni];
#pragma unroll
    for (int mi = 0; mi < 4; ++mi)
#pragma unroll
      for (int ni = 0; ni < 4; ++ni)
        acc[mi][ni] = __builtin_amdgcn_mfma_f32_16x16x32_bf16(af[mi], bfr[ni],
                                                              acc[mi][ni], 0, 0, 0);
    __syncthreads();
  }

  const int row0 = bm * 128 + wr * 64;
  const int col0 = bn * 128 + wc * 64;
#pragma unroll
  for (int ni = 0; ni < 4; ++ni) {
    const int col = col0 + ni * 16 + (lane & 15);
    const float bias = kb[col];
#pragma unroll
    for (int mi = 0; mi < 4; ++mi)
#pragma unroll
      for (int r = 0; r < 4; ++r) {
        const int row = row0 + mi * 16 + (lane >> 4) * 4 + r;
        C[(size_t)row * 2048 + col] = f2bf(acc[mi][ni][r] + bias);
      }
  }
}

// ---------------------------------------------------------------------------
// 8a. attn_score: 1024 blocks = (b,h) x 8 chunks of 256 positions.
//     K layout [16384][2048].  scores[bh][t], per-chunk max -> gmaxp.
// ---------------------------------------------------------------------------
__global__ __launch_bounds__(256) void attn_score_kernel(
    const unsigned short* __restrict__ Km, const float* __restrict__ qv,
    const float* __restrict__ tab, float* __restrict__ scores,
    float* __restrict__ gmaxp) {
  const int bh = blockIdx.x >> 3, chunk = blockIdx.x & 7;
  const int b = bh >> 4, h = bh & 15;
  const int tid = threadIdx.x, lane = tid & 63, wave = tid >> 6;
  const int seg = lane & 15, rg = lane >> 4;
  const int t0 = chunk * 256;

  float qf[8];
  {
    const float* qp = qv + (size_t)bh * 128 + seg * 8;
#pragma unroll
    for (int j = 0; j < 8; ++j) qf[j] = qp[j];
  }
  const unsigned short* Kbase = Km + ((size_t)b * 2048) * 2048 + h * 128;

  float lmax = -3.4e38f;
  for (int it = 0; it < 16; ++it) {
    const int t = t0 + it * 16 + wave * 4 + rg;
    us8 uv = *(const us8*)(Kbase + (size_t)t * 2048 + seg * 8);
    float k[8];
#pragma unroll
    for (int j = 0; j < 8; ++j) k[j] = bf2f(uv[j]);
    if (seg < 8) {
#pragma unroll
      for (int p = 0; p < 4; ++p) {
        const int i = seg * 4 + p;
        const float sn = tab[t * 64 + i], cs = tab[t * 64 + 32 + i];
        const float e = k[2 * p], o = k[2 * p + 1];
        k[2 * p]     = e * cs - o * sn;
        k[2 * p + 1] = o * cs + e * sn;
      }
    }
    float part = 0.f;
#pragma unroll
    for (int j = 0; j < 8; ++j) part += qf[j] * k[j];
    part += __shfl_xor(part, 1);
    part += __shfl_xor(part, 2);
    part += __shfl_xor(part, 4);
    part += __shfl_xor(part, 8);
    if (seg == 0) scores[(size_t)bh * 2048 + t] = part;
    lmax = fmaxf(lmax, part);
  }
  for (int m = 1; m < 64; m <<= 1) lmax = fmaxf(lmax, __shfl_xor(lmax, m));
  __shared__ float rmax[4];
  if (lane == 0) rmax[wave] = lmax;
  __syncthreads();
  if (tid == 0)
    gmaxp[blockIdx.x] = fmaxf(fmaxf(rmax[0], rmax[1]), fmaxf(rmax[2], rmax[3]));
}

// ---------------------------------------------------------------------------
// 8b. attn_z: per (b,h): gmax, w=exp(s-gmax) -> sw_t[b][t][h] (transposed),
//     Z[bh].  128 blocks.
// ---------------------------------------------------------------------------
__global__ __launch_bounds__(256) void attn_z_kernel(
    const float* __restrict__ scores, const float* __restrict__ gmaxp,
    float* __restrict__ sw_t, float* __restrict__ Z) {
  const int bh = blockIdx.x, b = bh >> 4, h = bh & 15;
  const int tid = threadIdx.x, lane = tid & 63, wave = tid >> 6;
  float gmax = -3.4e38f;
#pragma unroll
  for (int i = 0; i < 8; ++i) gmax = fmaxf(gmax, gmaxp[bh * 8 + i]);
  float lsum = 0.f;
  for (int t = tid; t < 2048; t += 256) {
    const float w = __expf(scores[(size_t)bh * 2048 + t] - gmax);
    sw_t[((size_t)b * 2048 + t) * 16 + h] = w;
    lsum += w;
  }
  for (int m = 1; m < 64; m <<= 1) lsum += __shfl_xor(lsum, m);
  __shared__ float rz[4];
  if (lane == 0) rz[wave] = lsum;
  __syncthreads();
  if (tid == 0) Z[bh] = rz[0] + rz[1] + rz[2] + rz[3];
}

// ---------------------------------------------------------------------------
// 8c. attn_wsum: partial weighted sums of hs rows, all 16 heads at once.
//     grid (8 b, 4 ech, 8 tc); thread owns 2 consecutive e's.
//     part[tc][b][h][e] += sw_t[b][t][h] * hs[b][t][e]
// ---------------------------------------------------------------------------
__global__ __launch_bounds__(256) void attn_wsum_kernel(
    const unsigned short* __restrict__ hs, const float* __restrict__ sw_t,
    float* __restrict__ part) {
  const int b = blockIdx.x, ech = blockIdx.y, tc = blockIdx.z;
  const int tid = threadIdx.x;
  const int e = ech * 512 + tid * 2;
  float a0[16], a1[16];
#pragma unroll
  for (int h = 0; h < 16; ++h) { a0[h] = 0.f; a1[h] = 0.f; }
  const unsigned short* hp = hs + ((size_t)b * 2048 + tc * 256) * 2048 + e;
  const float* wp = sw_t + ((size_t)b * 2048 + tc * 256) * 16;
  for (int tt = 0; tt < 256; ++tt) {
    const unsigned hv = *(const unsigned*)(hp + (size_t)tt * 2048);
    const float h0 = __uint_as_float(hv << 16);
    const float h1 = __uint_as_float(hv & 0xffff0000u);
    const float4 w0 = *(const float4*)(wp + tt * 16 + 0);
    const float4 w1 = *(const float4*)(wp + tt * 16 + 4);
    const float4 w2 = *(const float4*)(wp + tt * 16 + 8);
    const float4 w3 = *(const float4*)(wp + tt * 16 + 12);
    const float wv[16] = {w0.x, w0.y, w0.z, w0.w, w1.x, w1.y, w1.z, w1.w,
                          w2.x, w2.y, w2.z, w2.w, w3.x, w3.y, w3.z, w3.w};
#pragma unroll
    for (int h = 0; h < 16; ++h) {
      a0[h] += wv[h] * h0;
      a1[h] += wv[h] * h1;
    }
  }
#pragma unroll
  for (int h = 0; h < 16; ++h) {
    float2 st = {a0[h], a1[h]};
    *(float2*)(part + (((size_t)tc * 8 + b) * 16 + h) * 2048 + e) = st;
  }
}

// ---------------------------------------------------------------------------
// 8d. attn_comb: wsumN[bh][e] = (sum_tc part) / Z[bh].  128 blocks.
// ---------------------------------------------------------------------------
__global__ __launch_bounds__(256) void attn_comb_kernel(
    const float* __restrict__ part, const float* __restrict__ Z,
    float* __restrict__ wsumN) {
  const int bh = blockIdx.x, b = bh >> 4, h = bh & 15;
  const float zi = 1.f / Z[bh];
  for (int e = threadIdx.x; e < 2048; e += 256) {
    float s = 0.f;
#pragma unroll
    for (int tc = 0; tc < 8; ++tc)
      s += part[(((size_t)tc * 8 + b) * 16 + h) * 2048 + e];
    wsumN[(size_t)bh * 2048 + e] = s * zi;
  }
}

// ---------------------------------------------------------------------------
// 8e. attn_vgemv: aout[bh][d] = v_w[h*128+d] . wsumN[bh] + v_b[h*128+d]
//     512 blocks x 4 waves; one wave per (h,d), 8 batches per wave.
// ---------------------------------------------------------------------------
__global__ __launch_bounds__(256) void attn_vgemv_kernel(
    const float* __restrict__ vw, const float* __restrict__ vb,
    const float* __restrict__ wsumN, float* __restrict__ aout) {
  const int tid = threadIdx.x, lane = tid & 63, wave = tid >> 6;
  const int gw = blockIdx.x * 4 + wave;          // (h,d) in [0,2048)
  const int h = gw >> 7, d = gw & 127;
  const float* vr = vw + (size_t)gw * 2048;
  float p[8] = {0, 0, 0, 0, 0, 0, 0, 0};
#pragma unroll
  for (int it = 0; it < 8; ++it) {
    const int k = it * 256 + lane * 4;
    float4 wv = *(const float4*)(vr + k);
#pragma unroll
    for (int b = 0; b < 8; ++b) {
      float4 xv = *(const float4*)(wsumN + ((size_t)b * 16 + h) * 2048 + k);
      p[b] += wv.x * xv.x + wv.y * xv.y + wv.z * xv.z + wv.w * xv.w;
    }
  }
#pragma unroll
  for (int b = 0; b < 8; ++b)
    for (int m = 1; m < 64; m <<= 1) p[b] += __shfl_xor(p[b], m);
  if (lane == 0) {
    const float bb = vb[gw];
#pragma unroll
    for (int b = 0; b < 8; ++b)
      aout[((size_t)b * 16 + h) * 128 + d] = p[b] + bb;
  }
}

// ---------------------------------------------------------------------------
extern "C" void kernel_launch(void* const* d_in, const int* in_sizes, int n_in,
                              void* d_out, int out_size, void* d_ws, size_t ws_size,
                              hipStream_t stream) {
  (void)in_sizes; (void)n_in; (void)out_size; (void)ws_size;
  const float* hidden = (const float*)d_in[0];
  const int*   ids    = (const int*)d_in[1];
  const float* ln_w   = (const float*)d_in[2];
  const float* ln_b   = (const float*)d_in[3];
  const float* q_w    = (const float*)d_in[4];
  const float* q_b    = (const float*)d_in[5];
  const float* k_w    = (const float*)d_in[6];
  const float* k_b    = (const float*)d_in[7];
  const float* v_w    = (const float*)d_in[8];
  const float* v_b    = (const float*)d_in[9];
  const float* out_w  = (const float*)d_in[10];
  const float* out_b  = (const float*)d_in[11];
  float* out = (float*)d_out;

  char* ws = (char*)d_ws;
  unsigned short* hs  = (unsigned short*)ws; ws += (size_t)16384 * 2048 * 2;  // 64 MB
  unsigned short* Wk  = (unsigned short*)ws; ws += (size_t)2048 * 2048 * 2;   // 8 MB
  unsigned short* Km  = (unsigned short*)ws; ws += (size_t)16384 * 2048 * 2;  // 64 MB
  float* sctab  = (float*)ws; ws += (size_t)2048 * 64 * 4;                    // 512 KB
  float* qv     = (float*)ws; ws += (size_t)8 * 2048 * 4;
  float* hl     = (float*)ws; ws += (size_t)8 * 2048 * 4;
  float* aout   = (float*)ws; ws += (size_t)8 * 2048 * 4;
  float* scores = (float*)ws; ws += (size_t)128 * 2048 * 4;                   // 1 MB
  float* gmaxp  = (float*)ws; ws += 1024 * 4;
  float* sw_t   = (float*)ws; ws += (size_t)8 * 2048 * 16 * 4;                // 1 MB
  float* Zb     = (float*)ws; ws += 128 * 4;
  float* part   = (float*)ws; ws += (size_t)8 * 8 * 16 * 2048 * 4;            // 8 MB
  float* wsumN  = (float*)ws; ws += (size_t)128 * 2048 * 4;                   // 1 MB
  int*   ixp    = (int*)ws;  ws += 256;

  ix_kernel<<<8, 256, 0, stream>>>(ids, ixp);
  ln_kernel<<<16384, 256, 0, stream>>>(hidden, ln_w, ln_b, hs);
  f2bf_kernel<<<4096, 256, 0, stream>>>(k_w, Wk);
  sctab_kernel<<<2048, 64, 0, stream>>>(sctab);
  hlast_kernel<<<8, 256, 0, stream>>>(hidden, ln_w, ln_b, ixp, hl);
  gemv8_kernel<<<512, 256, 0, stream>>>(hl, q_w, q_b, qv);
  gemm_k_kernel<<<dim3(128, 16), 256, 0, stream>>>(hs, Wk, k_b, Km);
  attn_score_kernel<<<1024, 256, 0, stream>>>(Km, qv, sctab, scores, gmaxp);
  attn_z_kernel<<<128, 256, 0, stream>>>(scores, gmaxp, sw_t, Zb);
  attn_wsum_kernel<<<dim3(8, 4, 8), 256, 0, stream>>>(hs, sw_t, part);
  attn_comb_kernel<<<128, 256, 0, stream>>>(part, Zb, wsumN);
  attn_vgemv_kernel<<<512, 256, 0, stream>>>(v_w, v_b, wsumN, aout);
  gemv8_kernel<<<512, 256, 0, stream>>>(aout, out_w, out_b, out);
}

// Round 4
// 511.636 us; speedup vs baseline: 1.6934x; 1.0480x over previous
//
#include <hip/hip_runtime.h>
#include <hip/hip_bf16.h>
#include <cstdint>
#include <cstddef>

// ---------------------------------------------------------------------------
// NostARHeadAttention: LN -> {Q(last), K} proj -> RoPE(K) -> 1-query attn
// with V-elimination (out_head = v_w_head @ softmax-weighted sum of hs + v_b).
// R3: (1) RoPE + q-dot fused into GEMM epilogue (Km never materialized,
// attn_score kernel removed); (2) attn_wsum reads w via LDS broadcast;
// (3) ix+hlast fused.  B=8, S=2048, E=2048, H=16, D=128, ROT=64.
// ---------------------------------------------------------------------------

using bf16x8 = __attribute__((ext_vector_type(8))) __bf16;
using f32x4  = __attribute__((ext_vector_type(4))) float;

__device__ __forceinline__ float bf2f(unsigned short u) {
  return __uint_as_float(((unsigned)u) << 16);
}
__device__ __forceinline__ unsigned short f2bf(float f) {
  unsigned u = __float_as_uint(f);
  u += 0x7fffu + ((u >> 16) & 1u);   // RNE
  return (unsigned short)(u >> 16);
}

__device__ __forceinline__ void gld16(const void* g, void* l) {
  __builtin_amdgcn_global_load_lds((__attribute__((address_space(1))) void*)g,
                                   (__attribute__((address_space(3))) void*)l,
                                   16, 0, 0);
}

// ---------------------------------------------------------------------------
// 1. fused: last non-pad index per batch + LN of that row -> fp32
// ---------------------------------------------------------------------------
__global__ __launch_bounds__(256) void ixhlast_kernel(
    const int* __restrict__ ids, const float* __restrict__ x,
    const float* __restrict__ gw, const float* __restrict__ gb,
    float* __restrict__ hl) {
  const int b = blockIdx.x, tid = threadIdx.x;
  const int wave = tid >> 6, lane = tid & 63;
  // phase 1: last non-pad index
  int best = -1;
  for (int t = tid; t < 2048; t += 256)
    if (ids[b * 2048 + t] != 50257) best = (t > best) ? t : best;
  for (int m = 1; m < 64; m <<= 1) {
    int o = __shfl_xor(best, m);
    best = (o > best) ? o : best;
  }
  __shared__ int rb[4];
  if (lane == 0) rb[wave] = best;
  __syncthreads();
  int ix = rb[0];
  for (int w = 1; w < 4; ++w) ix = (rb[w] > ix) ? rb[w] : ix;
  ix = (ix < 0) ? 0 : ix;
  // phase 2: LN of row ix
  const float* xr = x + ((size_t)b * 2048 + ix) * 2048;
  float4 a = ((const float4*)xr)[tid];
  float4 c = ((const float4*)xr)[tid + 256];
  float s  = a.x + a.y + a.z + a.w + c.x + c.y + c.z + c.w;
  float ss = a.x*a.x + a.y*a.y + a.z*a.z + a.w*a.w +
             c.x*c.x + c.y*c.y + c.z*c.z + c.w*c.w;
  for (int m = 1; m < 64; m <<= 1) { s += __shfl_xor(s, m); ss += __shfl_xor(ss, m); }
  __shared__ float rs[4], rss[4];
  if (lane == 0) { rs[wave] = s; rss[wave] = ss; }
  __syncthreads();
  s  = rs[0] + rs[1] + rs[2] + rs[3];
  ss = rss[0] + rss[1] + rss[2] + rss[3];
  const float mu = s * (1.f / 2048.f);
  const float var = ss * (1.f / 2048.f) - mu * mu;
  const float r = rsqrtf(var + 1e-5f);
  const int i0 = tid * 4, i1 = 1024 + tid * 4;
  float* yo = hl + (size_t)b * 2048;
  yo[i0 + 0] = (a.x - mu) * r * gw[i0 + 0] + gb[i0 + 0];
  yo[i0 + 1] = (a.y - mu) * r * gw[i0 + 1] + gb[i0 + 1];
  yo[i0 + 2] = (a.z - mu) * r * gw[i0 + 2] + gb[i0 + 2];
  yo[i0 + 3] = (a.w - mu) * r * gw[i0 + 3] + gb[i0 + 3];
  yo[i1 + 0] = (c.x - mu) * r * gw[i1 + 0] + gb[i1 + 0];
  yo[i1 + 1] = (c.y - mu) * r * gw[i1 + 1] + gb[i1 + 1];
  yo[i1 + 2] = (c.z - mu) * r * gw[i1 + 2] + gb[i1 + 2];
  yo[i1 + 3] = (c.w - mu) * r * gw[i1 + 3] + gb[i1 + 3];
}

// ---------------------------------------------------------------------------
// 2. LayerNorm all rows -> bf16
// ---------------------------------------------------------------------------
__global__ __launch_bounds__(256) void ln_kernel(const float* __restrict__ x,
                                                 const float* __restrict__ gw,
                                                 const float* __restrict__ gb,
                                                 unsigned short* __restrict__ y) {
  const size_t row = blockIdx.x;
  const float* xr = x + row * 2048;
  const int tid = threadIdx.x;
  float4 a = ((const float4*)xr)[tid];
  float4 b = ((const float4*)xr)[tid + 256];
  float s  = a.x + a.y + a.z + a.w + b.x + b.y + b.z + b.w;
  float ss = a.x*a.x + a.y*a.y + a.z*a.z + a.w*a.w +
             b.x*b.x + b.y*b.y + b.z*b.z + b.w*b.w;
  for (int m = 1; m < 64; m <<= 1) { s += __shfl_xor(s, m); ss += __shfl_xor(ss, m); }
  __shared__ float rs[4], rss[4];
  const int wave = tid >> 6, lane = tid & 63;
  if (lane == 0) { rs[wave] = s; rss[wave] = ss; }
  __syncthreads();
  s  = rs[0] + rs[1] + rs[2] + rs[3];
  ss = rss[0] + rss[1] + rss[2] + rss[3];
  const float mu = s * (1.f / 2048.f);
  const float var = ss * (1.f / 2048.f) - mu * mu;
  const float r = rsqrtf(var + 1e-5f);
  unsigned short o[8];
  const int i0 = tid * 4, i1 = 1024 + tid * 4;
  o[0] = f2bf((a.x - mu) * r * gw[i0 + 0] + gb[i0 + 0]);
  o[1] = f2bf((a.y - mu) * r * gw[i0 + 1] + gb[i0 + 1]);
  o[2] = f2bf((a.z - mu) * r * gw[i0 + 2] + gb[i0 + 2]);
  o[3] = f2bf((a.w - mu) * r * gw[i0 + 3] + gb[i0 + 3]);
  o[4] = f2bf((b.x - mu) * r * gw[i1 + 0] + gb[i1 + 0]);
  o[5] = f2bf((b.y - mu) * r * gw[i1 + 1] + gb[i1 + 1]);
  o[6] = f2bf((b.z - mu) * r * gw[i1 + 2] + gb[i1 + 2]);
  o[7] = f2bf((b.w - mu) * r * gw[i1 + 3] + gb[i1 + 3]);
  ushort4 p0 = {o[0], o[1], o[2], o[3]};
  ushort4 p1 = {o[4], o[5], o[6], o[7]};
  *(ushort4*)(y + row * 2048 + i0) = p0;
  *(ushort4*)(y + row * 2048 + i1) = p1;
}

// ---------------------------------------------------------------------------
// 3. fp32 -> bf16 weight convert (k_w)
// ---------------------------------------------------------------------------
__global__ __launch_bounds__(256) void f2bf_kernel(const float* __restrict__ src,
                                                   unsigned short* __restrict__ dst) {
  const size_t i = (size_t)blockIdx.x * 256 + threadIdx.x;
  float4 v = ((const float4*)src)[i];
  ushort4 o = {f2bf(v.x), f2bf(v.y), f2bf(v.z), f2bf(v.w)};
  ((ushort4*)dst)[i] = o;
}

// ---------------------------------------------------------------------------
// 4. sin/cos table: tab[t*32+i] = (sin, cos)(t * 10000^(-i/32))
// ---------------------------------------------------------------------------
__global__ void sctab_kernel(float2* __restrict__ tab) {
  const int t = blockIdx.x, i = threadIdx.x;   // 32 threads
  const float inv = powf(10000.f, -(float)i / 32.f);
  const float ang = (float)t * inv;
  tab[t * 32 + i] = make_float2(sinf(ang), cosf(ang));
}

// ---------------------------------------------------------------------------
// 5. GEMV: Y[8][2048] = X[8][2048] @ W^T + bias (fp32), 512 blocks.
// ---------------------------------------------------------------------------
__global__ __launch_bounds__(256) void gemv8_kernel(const float* __restrict__ X,
                                                    const float* __restrict__ W,
                                                    const float* __restrict__ bias,
                                                    float* __restrict__ Y) {
  const int tid = threadIdx.x, lane = tid & 63, wave = tid >> 6;
  const int e = blockIdx.x * 4 + wave;
  const float* wr = W + (size_t)e * 2048;
  float p[8] = {0, 0, 0, 0, 0, 0, 0, 0};
#pragma unroll
  for (int it = 0; it < 8; ++it) {
    const int k = it * 256 + lane * 4;
    float4 wv = *(const float4*)(wr + k);
#pragma unroll
    for (int b = 0; b < 8; ++b) {
      float4 xv = *(const float4*)(X + b * 2048 + k);
      p[b] += wv.x * xv.x + wv.y * xv.y + wv.z * xv.z + wv.w * xv.w;
    }
  }
#pragma unroll
  for (int b = 0; b < 8; ++b)
    for (int m = 1; m < 64; m <<= 1) p[b] += __shfl_xor(p[b], m);
  if (lane == 0) {
    const float bb = bias[e];
#pragma unroll
    for (int b = 0; b < 8; ++b) Y[(size_t)b * 2048 + e] = p[b] + bb;
  }
}

// ---------------------------------------------------------------------------
// 6. K GEMM + fused bias/RoPE/q-dot epilogue.
//    C tile (bm: 128 tokens, bn: head h cols).  Epilogue rotates K pairs via
//    shfl_xor(.,1), dots with q[b,h], reduces -> scores[bh][t] + chunk max.
//    Km is never written.
// ---------------------------------------------------------------------------
__global__ __launch_bounds__(256) void gemm_kscore_kernel(
    const unsigned short* __restrict__ A, const unsigned short* __restrict__ W,
    const float* __restrict__ kb, const float* __restrict__ qv,
    const float2* __restrict__ tab, float* __restrict__ scores,
    float* __restrict__ gmaxp) {
  constexpr int K = 2048;
  __shared__ unsigned short As[128 * 32];
  __shared__ unsigned short Bs[128 * 32];
  const int tid = threadIdx.x;
  const int lane = tid & 63, wave = tid >> 6;
  const int wr = wave >> 1, wc = wave & 1;
  const int bm = blockIdx.x, bn = blockIdx.y;

  const unsigned short* Ap = A + ((size_t)(bm * 128 + (tid >> 2))) * K + (tid & 3) * 8;
  const unsigned short* Bp = W + ((size_t)(bn * 128 + (tid >> 2))) * K + (tid & 3) * 8;
  unsigned short* lA0 = As + wave * 512;
  unsigned short* lA1 = As + 2048 + wave * 512;
  unsigned short* lB0 = Bs + wave * 512;
  unsigned short* lB1 = Bs + 2048 + wave * 512;

  f32x4 acc[4][4];
#pragma unroll
  for (int i = 0; i < 4; ++i)
#pragma unroll
    for (int j = 0; j < 4; ++j) acc[i][j] = (f32x4){0.f, 0.f, 0.f, 0.f};

  const unsigned short* aPtr[4];
  const unsigned short* bPtr[4];
#pragma unroll
  for (int mi = 0; mi < 4; ++mi)
    aPtr[mi] = As + (wr * 64 + mi * 16 + (lane & 15)) * 32 + (lane >> 4) * 8;
#pragma unroll
  for (int ni = 0; ni < 4; ++ni)
    bPtr[ni] = Bs + (wc * 64 + ni * 16 + (lane & 15)) * 32 + (lane >> 4) * 8;

  for (int kt = 0; kt < K / 32; ++kt) {
    const int ko = kt * 32;
    gld16(Ap + ko,          lA0);
    gld16(Ap + ko + 64 * K, lA1);
    gld16(Bp + ko,          lB0);
    gld16(Bp + ko + 64 * K, lB1);
    __syncthreads();
    bf16x8 af[4], bfr[4];
#pragma unroll
    for (int mi = 0; mi < 4; ++mi) af[mi] = *(const bf16x8*)aPtr[mi];
#pragma unroll
    for (int ni = 0; ni < 4; ++ni) bfr[ni] = *(const bf16x8*)bPtr[ni];
#pragma unroll
    for (int mi = 0; mi < 4; ++mi)
#pragma unroll
      for (int ni = 0; ni < 4; ++ni)
        acc[mi][ni] = __builtin_amdgcn_mfma_f32_16x16x32_bf16(af[mi], bfr[ni],
                                                              acc[mi][ni], 0, 0, 0);
    __syncthreads();
  }

  // ---- fused epilogue: bias + RoPE + q-dot -> scores ----
  const int b  = bm >> 4;
  const int h  = bn;
  const int s0 = (bm & 15) * 128;
  const int rg = lane >> 4, l15 = lane & 15;
  float qreg[4], breg[4];
#pragma unroll
  for (int ni = 0; ni < 4; ++ni) {
    const int c = wc * 64 + ni * 16 + l15;
    qreg[ni] = qv[((size_t)b * 16 + h) * 128 + c];
    breg[ni] = kb[h * 128 + c];
  }
  float rowsum[4][4];
#pragma unroll
  for (int mi = 0; mi < 4; ++mi)
#pragma unroll
    for (int r = 0; r < 4; ++r) rowsum[mi][r] = 0.f;

  if (wc == 0) {   // cols 0..63 of the head: RoPE (wave-uniform branch)
    const bool even = (lane & 1) == 0;
#pragma unroll
    for (int ni = 0; ni < 4; ++ni) {
      const int i = (ni * 16 + l15) >> 1;
#pragma unroll
      for (int mi = 0; mi < 4; ++mi)
#pragma unroll
        for (int r = 0; r < 4; ++r) {
          const int t = s0 + wr * 64 + mi * 16 + rg * 4 + r;
          float kv = acc[mi][ni][r] + breg[ni];
          const float kp = __shfl_xor(kv, 1);
          const float2 sc = tab[t * 32 + i];
          kv = even ? (kv * sc.y - kp * sc.x) : (kv * sc.y + kp * sc.x);
          rowsum[mi][r] += kv * qreg[ni];
        }
    }
  } else {         // cols 64..127: no RoPE
#pragma unroll
    for (int ni = 0; ni < 4; ++ni)
#pragma unroll
      for (int mi = 0; mi < 4; ++mi)
#pragma unroll
        for (int r = 0; r < 4; ++r)
          rowsum[mi][r] += (acc[mi][ni][r] + breg[ni]) * qreg[ni];
  }
#pragma unroll
  for (int mi = 0; mi < 4; ++mi)
#pragma unroll
    for (int r = 0; r < 4; ++r) {
      float v = rowsum[mi][r];
      v += __shfl_xor(v, 1);
      v += __shfl_xor(v, 2);
      v += __shfl_xor(v, 4);
      v += __shfl_xor(v, 8);
      rowsum[mi][r] = v;
    }
  __shared__ float sS[4][64];
  __shared__ float sMax[2];
  if (l15 == 0) {
#pragma unroll
    for (int mi = 0; mi < 4; ++mi)
#pragma unroll
      for (int r = 0; r < 4; ++r)
        sS[wave][mi * 16 + rg * 4 + r] = rowsum[mi][r];
  }
  __syncthreads();
  if (tid < 128) {
    const int half = tid >> 6, rl = tid & 63;
    const float sc = sS[half * 2][rl] + sS[half * 2 + 1][rl];
    scores[((size_t)b * 16 + h) * 2048 + s0 + tid] = sc;
    float v = sc;
    for (int m = 1; m < 64; m <<= 1) v = fmaxf(v, __shfl_xor(v, m));
    if (rl == 0) sMax[half] = v;
  }
  __syncthreads();
  if (tid == 0)
    gmaxp[(((size_t)b * 16 + h) << 4) + (bm & 15)] = fmaxf(sMax[0], sMax[1]);
}

// ---------------------------------------------------------------------------
// 7. attn_z: per (b,h): gmax over 16 chunks, w=exp(s-gmax) -> sw_t[b][t][16h],
//    Z[bh].  128 blocks.
// ---------------------------------------------------------------------------
__global__ __launch_bounds__(256) void attn_z_kernel(
    const float* __restrict__ scores, const float* __restrict__ gmaxp,
    float* __restrict__ sw_t, float* __restrict__ Z) {
  const int bh = blockIdx.x, b = bh >> 4, h = bh & 15;
  const int tid = threadIdx.x, lane = tid & 63, wave = tid >> 6;
  float gmax = -3.4e38f;
#pragma unroll
  for (int i = 0; i < 16; ++i) gmax = fmaxf(gmax, gmaxp[bh * 16 + i]);
  float lsum = 0.f;
  for (int t = tid; t < 2048; t += 256) {
    const float w = __expf(scores[(size_t)bh * 2048 + t] - gmax);
    sw_t[((size_t)b * 2048 + t) * 16 + h] = w;
    lsum += w;
  }
  for (int m = 1; m < 64; m <<= 1) lsum += __shfl_xor(lsum, m);
  __shared__ float rz[4];
  if (lane == 0) rz[wave] = lsum;
  __syncthreads();
  if (tid == 0) Z[bh] = rz[0] + rz[1] + rz[2] + rz[3];
}

// ---------------------------------------------------------------------------
// 8. attn_wsum: part[tc][b][h][e] = sum_{t in chunk} w[b,t,h]*hs[b,t,e].
//    w staged in LDS once (8 KB), read via same-address broadcast.
//    grid (8 b, 4 ech of 512 e, 16 tc of 128 t); thread owns 2 e.
// ---------------------------------------------------------------------------
__global__ __launch_bounds__(256) void attn_wsum_kernel(
    const unsigned short* __restrict__ hs, const float* __restrict__ sw_t,
    float* __restrict__ part) {
  const int b = blockIdx.x, ech = blockIdx.y, tc = blockIdx.z;
  const int tid = threadIdx.x;
  const int e = ech * 512 + tid * 2;
  __shared__ float sw[128 * 16];   // 8 KB
  {
    const float4* src = (const float4*)(sw_t + ((size_t)b * 2048 + tc * 128) * 16);
    float4* dst = (float4*)sw;
    dst[tid] = src[tid];
    dst[tid + 256] = src[tid + 256];
  }
  __syncthreads();
  float a0[16], a1[16];
#pragma unroll
  for (int h = 0; h < 16; ++h) { a0[h] = 0.f; a1[h] = 0.f; }
  const unsigned short* hp = hs + ((size_t)b * 2048 + tc * 128) * 2048 + e;
#pragma unroll 2
  for (int tt = 0; tt < 128; ++tt) {
    const unsigned hv = *(const unsigned*)(hp + (size_t)tt * 2048);
    const float h0 = __uint_as_float(hv << 16);
    const float h1 = __uint_as_float(hv & 0xffff0000u);
    const float4 w0 = *(const float4*)(sw + tt * 16 + 0);
    const float4 w1 = *(const float4*)(sw + tt * 16 + 4);
    const float4 w2 = *(const float4*)(sw + tt * 16 + 8);
    const float4 w3 = *(const float4*)(sw + tt * 16 + 12);
    const float wv[16] = {w0.x, w0.y, w0.z, w0.w, w1.x, w1.y, w1.z, w1.w,
                          w2.x, w2.y, w2.z, w2.w, w3.x, w3.y, w3.z, w3.w};
#pragma unroll
    for (int h = 0; h < 16; ++h) {
      a0[h] += wv[h] * h0;
      a1[h] += wv[h] * h1;
    }
  }
#pragma unroll
  for (int h = 0; h < 16; ++h) {
    float2 st = {a0[h], a1[h]};
    *(float2*)(part + (((size_t)tc * 8 + b) * 16 + h) * 2048 + e) = st;
  }
}

// ---------------------------------------------------------------------------
// 9. attn_comb: wsumN[bh][e] = (sum_tc part) / Z[bh].  128 blocks.
// ---------------------------------------------------------------------------
__global__ __launch_bounds__(256) void attn_comb_kernel(
    const float* __restrict__ part, const float* __restrict__ Z,
    float* __restrict__ wsumN) {
  const int bh = blockIdx.x, b = bh >> 4, h = bh & 15;
  const float zi = 1.f / Z[bh];
  for (int e = threadIdx.x; e < 2048; e += 256) {
    float s = 0.f;
#pragma unroll
    for (int tc = 0; tc < 16; ++tc)
      s += part[(((size_t)tc * 8 + b) * 16 + h) * 2048 + e];
    wsumN[(size_t)bh * 2048 + e] = s * zi;
  }
}

// ---------------------------------------------------------------------------
// 10. attn_vgemv: aout[bh][d] = v_w[h*128+d] . wsumN[bh] + v_b[h*128+d]
// ---------------------------------------------------------------------------
__global__ __launch_bounds__(256) void attn_vgemv_kernel(
    const float* __restrict__ vw, const float* __restrict__ vb,
    const float* __restrict__ wsumN, float* __restrict__ aout) {
  const int tid = threadIdx.x, lane = tid & 63, wave = tid >> 6;
  const int gw = blockIdx.x * 4 + wave;          // (h,d) in [0,2048)
  const int h = gw >> 7, d = gw & 127;
  const float* vr = vw + (size_t)gw * 2048;
  float p[8] = {0, 0, 0, 0, 0, 0, 0, 0};
#pragma unroll
  for (int it = 0; it < 8; ++it) {
    const int k = it * 256 + lane * 4;
    float4 wv = *(const float4*)(vr + k);
#pragma unroll
    for (int b = 0; b < 8; ++b) {
      float4 xv = *(const float4*)(wsumN + ((size_t)b * 16 + h) * 2048 + k);
      p[b] += wv.x * xv.x + wv.y * xv.y + wv.z * xv.z + wv.w * xv.w;
    }
  }
#pragma unroll
  for (int b = 0; b < 8; ++b)
    for (int m = 1; m < 64; m <<= 1) p[b] += __shfl_xor(p[b], m);
  if (lane == 0) {
    const float bb = vb[gw];
#pragma unroll
    for (int b = 0; b < 8; ++b)
      aout[((size_t)b * 16 + h) * 128 + d] = p[b] + bb;
  }
}

// ---------------------------------------------------------------------------
extern "C" void kernel_launch(void* const* d_in, const int* in_sizes, int n_in,
                              void* d_out, int out_size, void* d_ws, size_t ws_size,
                              hipStream_t stream) {
  (void)in_sizes; (void)n_in; (void)out_size; (void)ws_size;
  const float* hidden = (const float*)d_in[0];
  const int*   ids    = (const int*)d_in[1];
  const float* ln_w   = (const float*)d_in[2];
  const float* ln_b   = (const float*)d_in[3];
  const float* q_w    = (const float*)d_in[4];
  const float* q_b    = (const float*)d_in[5];
  const float* k_w    = (const float*)d_in[6];
  const float* k_b    = (const float*)d_in[7];
  const float* v_w    = (const float*)d_in[8];
  const float* v_b    = (const float*)d_in[9];
  const float* out_w  = (const float*)d_in[10];
  const float* out_b  = (const float*)d_in[11];
  float* out = (float*)d_out;

  char* ws = (char*)d_ws;
  unsigned short* hs  = (unsigned short*)ws; ws += (size_t)16384 * 2048 * 2;  // 64 MB
  unsigned short* Wk  = (unsigned short*)ws; ws += (size_t)2048 * 2048 * 2;   // 8 MB
  float2* sctab = (float2*)ws; ws += (size_t)2048 * 32 * 8;                   // 512 KB
  float* qv     = (float*)ws; ws += (size_t)8 * 2048 * 4;
  float* hl     = (float*)ws; ws += (size_t)8 * 2048 * 4;
  float* aout   = (float*)ws; ws += (size_t)8 * 2048 * 4;
  float* scores = (float*)ws; ws += (size_t)128 * 2048 * 4;                   // 1 MB
  float* gmaxp  = (float*)ws; ws += (size_t)128 * 16 * 4;
  float* sw_t   = (float*)ws; ws += (size_t)8 * 2048 * 16 * 4;                // 1 MB
  float* Zb     = (float*)ws; ws += 128 * 4;
  float* part   = (float*)ws; ws += (size_t)16 * 8 * 16 * 2048 * 4;           // 16 MB
  float* wsumN  = (float*)ws; ws += (size_t)128 * 2048 * 4;                   // 1 MB

  ixhlast_kernel<<<8, 256, 0, stream>>>(ids, hidden, ln_w, ln_b, hl);
  ln_kernel<<<16384, 256, 0, stream>>>(hidden, ln_w, ln_b, hs);
  f2bf_kernel<<<4096, 256, 0, stream>>>(k_w, Wk);
  sctab_kernel<<<2048, 32, 0, stream>>>(sctab);
  gemv8_kernel<<<512, 256, 0, stream>>>(hl, q_w, q_b, qv);
  gemm_kscore_kernel<<<dim3(128, 16), 256, 0, stream>>>(hs, Wk, k_b, qv, sctab,
                                                        scores, gmaxp);
  attn_z_kernel<<<128, 256, 0, stream>>>(scores, gmaxp, sw_t, Zb);
  attn_wsum_kernel<<<dim3(8, 4, 16), 256, 0, stream>>>(hs, sw_t, part);
  attn_comb_kernel<<<128, 256, 0, stream>>>(part, Zb, wsumN);
  attn_vgemv_kernel<<<512, 256, 0, stream>>>(v_w, v_b, wsumN, aout);
  gemv8_kernel<<<512, 256, 0, stream>>>(aout, out_w, out_b, out);
}